// Round 1
// baseline (423.602 us; speedup 1.0000x reference)
//
#include <hip/hip_runtime.h>

// Haar DWT along S for x[B=32, S=4096, C=512] fp32.
// out[b, i, c]       = (x[b,2i,c] + x[b,2i+1,c]) / sqrt2   for i in [0, S/2)
// out[b, S/2+i, c]   = (x[b,2i,c] - x[b,2i+1,c]) / sqrt2
//
// Memory-bound: 256MB in + 256MB out. Each thread handles one (b, i, c4)
// with float4 vectorization along C (C=512 divisible by 4). Consecutive
// threads -> consecutive c -> fully coalesced 16B/lane loads and stores.

__global__ __launch_bounds__(256) void haar_dwt_kernel(
    const float4* __restrict__ x, float4* __restrict__ out,
    int total /* B * (S/2) * (C/4) */, int c4 /* C/4 */, int half_rows /* S/2 */) {
    const float inv_sqrt2 = 0.70710678118654752440f;

    int idx = blockIdx.x * blockDim.x + threadIdx.x;
    if (idx >= total) return;

    // idx = ((b * half_rows) + i) * c4 + c
    int c = idx % c4;
    int bi = idx / c4;       // b * half_rows + i
    int i = bi % half_rows;
    int b = bi / half_rows;

    // x row stride in float4 units = c4; x[b] has 2*half_rows rows
    const float4* xb = x + (size_t)b * (2 * half_rows) * c4;
    float4 a0 = xb[(size_t)(2 * i) * c4 + c];
    float4 a1 = xb[(size_t)(2 * i + 1) * c4 + c];

    float4 s, d;
    s.x = (a0.x + a1.x) * inv_sqrt2;
    s.y = (a0.y + a1.y) * inv_sqrt2;
    s.z = (a0.z + a1.z) * inv_sqrt2;
    s.w = (a0.w + a1.w) * inv_sqrt2;
    d.x = (a0.x - a1.x) * inv_sqrt2;
    d.y = (a0.y - a1.y) * inv_sqrt2;
    d.z = (a0.z - a1.z) * inv_sqrt2;
    d.w = (a0.w - a1.w) * inv_sqrt2;

    // out[b] also has 2*half_rows rows of c4 float4s
    float4* ob = out + (size_t)b * (2 * half_rows) * c4;
    ob[(size_t)i * c4 + c] = s;                       // cA at row i
    ob[(size_t)(half_rows + i) * c4 + c] = d;         // cD at row S/2+i
}

extern "C" void kernel_launch(void* const* d_in, const int* in_sizes, int n_in,
                              void* d_out, int out_size, void* d_ws, size_t ws_size,
                              hipStream_t stream) {
    const int B = 32, S = 4096, C = 512;
    const int half_rows = S / 2;      // 2048
    const int c4 = C / 4;             // 128
    const int total = B * half_rows * c4;  // 8,388,608 threads

    const float4* x = (const float4*)d_in[0];
    float4* out = (float4*)d_out;

    int block = 256;
    int grid = (total + block - 1) / block;
    haar_dwt_kernel<<<grid, block, 0, stream>>>(x, out, total, c4, half_rows);
}